// Round 14
// baseline (168.675 us; speedup 1.0000x reference)
//
#include <hip/hip_runtime.h>

typedef __bf16 bf16x8 __attribute__((ext_vector_type(8)));
typedef float f32x4 __attribute__((ext_vector_type(4)));
typedef unsigned short u16;
typedef unsigned long long u64;

#define HDIM 768
#define NHEADS 12
#define SEQ 1024
#define NBATCH 4
#define ROWS 4096      // B*T
#define QKV3 2304
#define INTERDIM 3072

__device__ __forceinline__ u16 f2bf(float f) {
  union { float f; unsigned int u; } v; v.f = f;
  unsigned int r = v.u + 0x7fffu + ((v.u >> 16) & 1u);
  return (u16)(r >> 16);
}

__device__ __forceinline__ float bf2f(u16 b) {
  union { unsigned int u; float f; } v; v.u = (unsigned int)b << 16;
  return v.f;
}

// async global->LDS, 16B per lane. LDS dest is wave-uniform base + lane*16.
__device__ __forceinline__ void gload16(const u16* g, u16* l) {
  __builtin_amdgcn_global_load_lds(
      (const __attribute__((address_space(1))) void*)g,
      (__attribute__((address_space(3))) void*)l, 16, 0, 0);
}

__device__ __forceinline__ unsigned ldsoff(const void* p) {
  return (unsigned)(unsigned long long)(const __attribute__((address_space(3))) char*)p;
}

// hardware transpose read: lane gets 4 bf16 at [a, a+32B, a+64B, a+96B]
__device__ __forceinline__ u64 tr8(unsigned a) {
  u64 r;
  asm volatile("ds_read_b64_tr_b16 %0, %1" : "=v"(r) : "v"(a));
  return r;
}

union B8 { u64 q[2]; bf16x8 v; };

// ---------------- fused pre-pass: x->bf16 + 4 weight transposes ----------------
__global__ __launch_bounds__(256) void k_prep(
    const float* __restrict__ x, u16* __restrict__ xb,
    const float* __restrict__ wqkv, u16* __restrict__ wqkvT,
    const float* __restrict__ wo, u16* __restrict__ woT,
    const float* __restrict__ w1, u16* __restrict__ w1T,
    const float* __restrict__ w2, u16* __restrict__ w2T) {
  __shared__ float tile[32][33];
  int bid = blockIdx.x, tid = threadIdx.x;
  if (bid < 3072) {
    int i = bid * 256 + tid;
    float4 f = reinterpret_cast<const float4*>(x)[i];
    ushort4 o;
    o.x = f2bf(f.x); o.y = f2bf(f.y); o.z = f2bf(f.z); o.w = f2bf(f.w);
    reinterpret_cast<ushort4*>(xb)[i] = o;
    return;
  }
  const float* in; u16* outp; int K, N, t;
  if (bid < 4800)      { in = wqkv; outp = wqkvT; K = 768;  N = 2304; t = bid - 3072; }
  else if (bid < 5376) { in = wo;   outp = woT;   K = 768;  N = 768;  t = bid - 4800; }
  else if (bid < 7680) { in = w1;   outp = w1T;   K = 768;  N = 3072; t = bid - 5376; }
  else                 { in = w2;   outp = w2T;   K = 3072; N = 768;  t = bid - 7680; }
  int ntx = N >> 5;
  int bx = t % ntx, by = t / ntx;
  int tx = tid & 31, ty = tid >> 5;
  int n0 = bx * 32, k0 = by * 32;
#pragma unroll
  for (int i = 0; i < 32; i += 8)
    tile[ty + i][tx] = in[(size_t)(k0 + ty + i) * N + n0 + tx];
  __syncthreads();
#pragma unroll
  for (int i = 0; i < 32; i += 8)
    outp[(size_t)(n0 + ty + i) * K + k0 + tx] = f2bf(tile[tx][ty + i]);
}

// ============ MFMA GEMM, BK=32, dbuf LDS, counted vmcnt (r13 config) ============
template<int BM, int BN, int MODE>
__global__ __launch_bounds__(256, 2) void k_gemm(
    const u16* __restrict__ A, const u16* __restrict__ Bt,
    int M, int N, int K, int ksplit,
    u16* __restrict__ obf,
    const float* __restrict__ e1, const float* __restrict__ e2) {
  constexpr int BK = 32;
  constexpr int WC = (BN == 128) ? 2 : 1;
  constexpr int WR = 4 / WC;
  constexpr int WM = BM / WR;
  constexpr int WN = BN / WC;
  constexpr int MFR = WM / 16;
  constexpr int NFR = WN / 16;
  constexpr int AISS = BM / 64;
  constexpr int BISS = BN / 64;
  constexpr int ISS = AISS + BISS;
  __shared__ u16 As[2][BM * BK];
  __shared__ u16 Bs[2][BN * BK];
  int tid = threadIdx.x, lane = tid & 63, wid = tid >> 6;
  int wr = wid / WC, wc = wid % WC;
  int fr = lane & 15, fg = lane >> 4, fk = fg * 8;

  int gx = gridDim.x;
  int nwg = gx * gridDim.y;
  int orig = blockIdx.y * gx + blockIdx.x;
  int swz = (orig & 7) * (nwg >> 3) + (orig >> 3);
  int bx = swz % gx, by = swz / gx;
  int m0 = by * BM, n0 = bx * BN;
  int Kc = K / ksplit, k0 = blockIdx.z * Kc;

  f32x4 acc[MFR][NFR] = {};

  int r = tid >> 2;
  int cswz = ((tid & 3) * 8) ^ (((r >> 1) & 3) << 3);
  const u16* Ag = A + (size_t)(m0 + r) * K + k0 + cswz;
  const u16* Bg = Bt + (size_t)(n0 + r) * K + k0 + cswz;

#define STAGE(t2) do {                                                   \
    int b_ = (t2) & 1; int kt_ = (t2) * BK;                              \
    _Pragma("unroll")                                                    \
    for (int i_ = 0; i_ < AISS; i_++)                                    \
      gload16(Ag + kt_ + (size_t)(i_ * 64) * K, &As[b_][i_ * 2048 + wid * 512]); \
    _Pragma("unroll")                                                    \
    for (int i_ = 0; i_ < BISS; i_++)                                    \
      gload16(Bg + kt_ + (size_t)(i_ * 64) * K, &Bs[b_][i_ * 2048 + wid * 512]); \
  } while (0)

  int ce = fk ^ (((fr >> 1) & 3) << 3);

  int nt = Kc / BK;
  STAGE(0);
  STAGE(1);

  for (int t = 0; t < nt; t++) {
    int cur = t & 1;
    if (t == nt - 1) {
      asm volatile("s_waitcnt vmcnt(0)\n\ts_barrier" ::: "memory");
    } else if constexpr (ISS == 6) {
      asm volatile("s_waitcnt vmcnt(6)\n\ts_barrier" ::: "memory");
    } else if constexpr (ISS == 4) {
      asm volatile("s_waitcnt vmcnt(4)\n\ts_barrier" ::: "memory");
    } else {
      asm volatile("s_waitcnt vmcnt(3)\n\ts_barrier" ::: "memory");
    }

    bf16x8 af[MFR], bv[NFR];
#pragma unroll
    for (int mi = 0; mi < MFR; mi++)
      af[mi] = *reinterpret_cast<const bf16x8*>(&As[cur][(wr * WM + mi * 16 + fr) * BK + ce]);
#pragma unroll
    for (int ni = 0; ni < NFR; ni++)
      bv[ni] = *reinterpret_cast<const bf16x8*>(&Bs[cur][(wc * WN + ni * 16 + fr) * BK + ce]);

    asm volatile("s_waitcnt lgkmcnt(0)\n\ts_barrier" ::: "memory");
    if (t + 2 < nt) STAGE(t + 2);

    __builtin_amdgcn_s_setprio(1);
#pragma unroll
    for (int mi = 0; mi < MFR; mi++)
#pragma unroll
      for (int ni = 0; ni < NFR; ni++)
        acc[mi][ni] = __builtin_amdgcn_mfma_f32_16x16x32_bf16(af[mi], bv[ni], acc[mi][ni], 0, 0, 0);
    __builtin_amdgcn_s_setprio(0);
  }
#undef STAGE

  u16* outp = (MODE == 3) ? obf + (size_t)blockIdx.z * ((size_t)M * N) : obf;
#pragma unroll
  for (int mi = 0; mi < MFR; mi++) {
#pragma unroll
    for (int ni = 0; ni < NFR; ni++) {
#pragma unroll
      for (int i = 0; i < 4; i++) {
        int row = m0 + wr * WM + mi * 16 + fg * 4 + i;
        int col = n0 + wc * WN + ni * 16 + fr;
        float v = acc[mi][ni][i];
        size_t idx = (size_t)row * N + col;
        if constexpr (MODE == 0) {
          outp[idx] = f2bf(v);
        } else if constexpr (MODE == 1) {
          outp[idx] = f2bf(e1[idx] + 0.2f * v + e2[col]);
        } else if constexpr (MODE == 2) {
          float t = v + e1[col];
          outp[idx] = f2bf(t > 0.f ? t : 0.f);
        } else {
          outp[idx] = f2bf(v);
        }
      }
    }
  }
}

// ---------------- ffn2 split-K reduce + residual + biases (bf16 inputs) ----------------
__global__ void k_ffn2_reduce(const u16* __restrict__ p, const u16* __restrict__ x1b,
                              const float* __restrict__ b2, const float* __restrict__ nb2,
                              float* __restrict__ out) {
  int i = blockIdx.x * 256 + threadIdx.x;
  int col4 = (i * 4) % HDIM;
  ushort4 xv = reinterpret_cast<const ushort4*>(x1b)[i];
  float4 bb = *reinterpret_cast<const float4*>(b2 + col4);
  float4 nn = *reinterpret_cast<const float4*>(nb2 + col4);
  float4 s;
  s.x = bf2f(xv.x) + bb.x + nn.x;
  s.y = bf2f(xv.y) + bb.y + nn.y;
  s.z = bf2f(xv.z) + bb.z + nn.z;
  s.w = bf2f(xv.w) + bb.w + nn.w;
#pragma unroll
  for (int z = 0; z < 4; z++) {
    ushort4 pv = reinterpret_cast<const ushort4*>(p + (size_t)z * ROWS * HDIM)[i];
    s.x += bf2f(pv.x); s.y += bf2f(pv.y); s.z += bf2f(pv.z); s.w += bf2f(pv.w);
  }
  reinterpret_cast<float4*>(out)[i] = s;
}

// ---------------- fused 2quad attention (4 waves, 64 q-rows/block) ----------------
// K consumed DIRECTLY from global (L2-resident via bh-chunked XCD grid) — no K
// staging. V double-buffered in LDS (tr8 layout), ONE barrier/tile. P per-wave
// LDS + tr8. den via ones-MFMA. K(t+1) frags issued right after last use of
// K(t); V(t+1) regs prefetched at tile top, written to LDS after PV reads.
// grid = 16 t0-chunks x 48 (b,h); bid = t0i*48 + bh; 48%8==0 -> XCD-pinned.
__global__ __launch_bounds__(256) void k_attn(
    const u16* __restrict__ qkv, const float* __restrict__ mask,
    const float* __restrict__ tau, u16* __restrict__ outp) {
  __shared__ u16 Vs[2][64 * 64];  // subtiled: block(sg,dj)=sg*4+dj, 4s x 16d
  __shared__ u16 Ps[4][1024];     // per-wave P^T subtiled
  int tid = threadIdx.x, lane = tid & 63, w = tid >> 6;
  int bid = blockIdx.x;
  int bh = bid % 48, t0i = bid / 48;
  int h = bh >> 2, b = bh & 3;
  int fr = lane & 15, fg = lane >> 4, fk = fg * 8;
  int rb = b * SEQ;
  float rs = 1.0f / (8.0f * tau[h]);
  float rs2 = rs * rs;

  int t0 = t0i * 64 + w * 16;
  const u16* qrow = qkv + (size_t)(rb + t0 + fr) * QKV3 + h * 64;
  bf16x8 aq0 = *reinterpret_cast<const bf16x8*>(qrow + fk);
  bf16x8 aq1 = *reinterpret_cast<const bf16x8*>(qrow + 32 + fk);

  const u16* kb = qkv + (size_t)rb * QKV3 + HDIM + h * 64;  // K rows base

  f32x4 acco[4] = {};
  f32x4 accd = {};

  // V staging (256 threads): row sr (0..63), 16-elem d-chunk c2 (0..3)
  int sr = tid >> 2, c2 = tid & 3;
  const u16* vg = qkv + (size_t)(rb + sr) * QKV3 + 2 * HDIM + h * 64 + c2 * 16;
  int vwo = ((sr >> 2) * 4 + c2) * 64 + (sr & 3) * 16;
  unsigned psb = ldsoff(&Ps[w][0]);
  unsigned vsb0 = ldsoff(&Vs[0][0]);

  __bf16 onev = (__bf16)1.0f;
  bf16x8 ones = {onev, onev, onev, onev, onev, onev, onev, onev};

  // prologue: V(0) -> Vs[0]; K(0) fragment loads
  int4 v0 = *reinterpret_cast<const int4*>(vg);
  int4 v1 = *reinterpret_cast<const int4*>(vg + 8);
  *reinterpret_cast<int4*>(&Vs[0][vwo]) = v0;
  *reinterpret_cast<int4*>(&Vs[0][vwo + 8]) = v1;
  bf16x8 bk[4][2];
#pragma unroll
  for (int sf = 0; sf < 4; sf++) {
    const u16* kr = kb + (size_t)(sf * 16 + fr) * QKV3;
    bk[sf][0] = *reinterpret_cast<const bf16x8*>(kr + fk);
    bk[sf][1] = *reinterpret_cast<const bf16x8*>(kr + 32 + fk);
  }
  __syncthreads();

  for (int t = 0; t < 16; t++) {
    int st = t * 64;
    unsigned vsb = vsb0 + (t & 1) * 8192;   // byte offset of current V buffer
    bool pf = (t < 15);

    // prefetch V(t+1) into regs (lands during this tile's compute)
    if (pf) {
      v0 = *reinterpret_cast<const int4*>(vg + (size_t)(st + 64) * QKV3);
      v1 = *reinterpret_cast<const int4*>(vg + (size_t)(st + 64) * QKV3 + 8);
    }

    // ---- QK^T (K frags in regs, loaded from L2 last tile) + P^T pack ----
#pragma unroll
    for (int sf = 0; sf < 4; sf++) {
      f32x4 s = {};
      s = __builtin_amdgcn_mfma_f32_16x16x32_bf16(aq0, bk[sf][0], s, 0, 0, 0);
      s = __builtin_amdgcn_mfma_f32_16x16x32_bf16(aq1, bk[sf][1], s, 0, 0, 0);
      float rm = rs2 * mask[b * SEQ + st + sf * 16 + fr];
      u64 pw = 0;
#pragma unroll
      for (int i = 0; i < 4; i++) {
        float wv = s[i] * s[i] * rm;
        pw |= (u64)f2bf(wv) << (16 * i);
      }
      *reinterpret_cast<u64*>(&Ps[w][(sf * 4 + (fr >> 2)) * 64 + (fr & 3) * 16 + fg * 4]) = pw;
    }

    // issue K(t+1) fragment loads now (fly across rest of tile + barrier)
    if (pf) {
#pragma unroll
      for (int sf = 0; sf < 4; sf++) {
        const u16* kr = kb + (size_t)(st + 64 + sf * 16 + fr) * QKV3;
        bk[sf][0] = *reinterpret_cast<const bf16x8*>(kr + fk);
        bk[sf][1] = *reinterpret_cast<const bf16x8*>(kr + 32 + fk);
      }
    }

    asm volatile("s_waitcnt lgkmcnt(0)" ::: "memory");
    __builtin_amdgcn_sched_barrier(0);

    // ---- PV via tr reads ----
    u64 pa0 = tr8(psb + (fg * 2 + 0) * 128 + fr * 2);
    u64 pa1 = tr8(psb + (fg * 2 + 1) * 128 + fr * 2);
    u64 pa2 = tr8(psb + (8 + fg * 2 + 0) * 128 + fr * 2);
    u64 pa3 = tr8(psb + (8 + fg * 2 + 1) * 128 + fr * 2);
    u64 vb[4][4];
#pragma unroll
    for (int df = 0; df < 4; df++) {
      vb[df][0] = tr8(vsb + ((fg * 2 + 0) * 4 + df) * 128 + fr * 2);
      vb[df][1] = tr8(vsb + ((fg * 2 + 1) * 4 + df) * 128 + fr * 2);
      vb[df][2] = tr8(vsb + ((8 + fg * 2 + 0) * 4 + df) * 128 + fr * 2);
      vb[df][3] = tr8(vsb + ((8 + fg * 2 + 1) * 4 + df) * 128 + fr * 2);
    }
    asm volatile("s_waitcnt lgkmcnt(0)" ::: "memory");
    __builtin_amdgcn_sched_barrier(0);

    B8 ap0, ap1;
    ap0.q[0] = pa0; ap0.q[1] = pa1;
    ap1.q[0] = pa2; ap1.q[1] = pa3;
#pragma unroll
    for (int df = 0; df < 4; df++) {
      B8 b0, b1;
      b0.q[0] = vb[df][0]; b0.q[1] = vb[df][1];
      b1.q[0] = vb[df][2]; b1.q[1] = vb[df][3];
      acco[df] = __builtin_amdgcn_mfma_f32_16x16x32_bf16(ap0.v, b0.v, acco[df], 0, 0, 0);
      acco[df] = __builtin_amdgcn_mfma_f32_16x16x32_bf16(ap1.v, b1.v, acco[df], 0, 0, 0);
    }
    accd = __builtin_amdgcn_mfma_f32_16x16x32_bf16(ap0.v, ones, accd, 0, 0, 0);
    accd = __builtin_amdgcn_mfma_f32_16x16x32_bf16(ap1.v, ones, accd, 0, 0, 0);

    // write V(t+1) into the other buffer; barrier publishes it for t+1 and
    // guarantees this tile's reads of Vs[cur] are globally done before t+2
    // overwrites it.
    if (pf) {
      u16* vdst = &Vs[(t + 1) & 1][vwo];
      *reinterpret_cast<int4*>(vdst) = v0;
      *reinterpret_cast<int4*>(vdst + 8) = v1;
    }
    __syncthreads();
  }

#pragma unroll
  for (int df = 0; df < 4; df++)
#pragma unroll
    for (int i = 0; i < 4; i++) {
      int t = t0 + fg * 4 + i;
      int col = h * 64 + df * 16 + fr;
      float o = acco[df][i] / (accd[i] + 1e-6f);
      outp[(size_t)(rb + t) * HDIM + col] = f2bf(o);
    }
}

extern "C" void kernel_launch(void* const* d_in, const int* in_sizes, int n_in,
                              void* d_out, int out_size, void* d_ws, size_t ws_size,
                              hipStream_t stream) {
  const float* x     = (const float*)d_in[0];
  const float* mask  = (const float*)d_in[1];
  const float* w_qkv = (const float*)d_in[2];
  const float* w_o   = (const float*)d_in[3];
  const float* tau   = (const float*)d_in[4];
  const float* w1    = (const float*)d_in[5];
  const float* b1    = (const float*)d_in[6];
  const float* w2    = (const float*)d_in[7];
  const float* b2    = (const float*)d_in[8];
  const float* nb1   = (const float*)d_in[9];
  const float* nb2   = (const float*)d_in[10];
  float* out = (float*)d_out;
  (void)ws_size; (void)in_sizes; (void)n_in; (void)out_size;

  char* base = (char*)d_ws;
  u16* partb = (u16*)base;                    // [4][ROWS][HDIM] bf16, live only in ffn2
  u16* xb    = (u16*)(base);
  u16* wqkvT = (u16*)(base + 6291456);
  u16* woT   = (u16*)(base + 9830400);
  u16* w1T   = (u16*)(base + 11010048);
  u16* qkvb  = (u16*)(base + 15728640);       // dead after attn
  u16* attnb = (u16*)(base + 34603008);
  u16* x1b   = (u16*)(base + 40894464);       // live through reduce
  u16* w2T   = (u16*)(base + 50331648);
  u16* hb    = (u16*)(base + 67633152);

  k_prep<<<9984, 256, 0, stream>>>(x, xb, w_qkv, wqkvT, w_o, woT, w1, w1T, w2, w2T);

  // qkv = x @ w_qkv -> bf16   (grid 18x16 = 288, 256-tile)
  k_gemm<256, 128, 0><<<dim3(QKV3 / 128, ROWS / 256), 256, 0, stream>>>(
      xb, wqkvT, ROWS, QKV3, HDIM, 1, qkvb, nullptr, nullptr);
  // attention (1D grid: 16 t0-chunks * 48 bh = 768, 256 threads)
  k_attn<<<768, 256, 0, stream>>>(qkvb, mask, tau, attnb);
  // x1 = bf16(x + 0.2*(attn @ w_o) + nb1)   (grid 12x32 = 384)
  k_gemm<128, 64, 1><<<dim3(HDIM / 64, ROWS / 128), 256, 0, stream>>>(
      attnb, woT, ROWS, HDIM, HDIM, 1, x1b, x, nb1);
  // h = relu(x1 @ w1 + b1)   (grid 24x32 = 768, 128^2 tile)
  k_gemm<128, 128, 2><<<dim3(INTERDIM / 128, ROWS / 128), 256, 0, stream>>>(
      x1b, w1T, ROWS, INTERDIM, HDIM, 1, hb, b1, nullptr);
  // ffn2 split-K=4 bf16 partials   (grid 6x32x4 = 768, 128^2 tile)
  k_gemm<128, 128, 3><<<dim3(HDIM / 128, ROWS / 128, 4), 256, 0, stream>>>(
      hb, w2T, ROWS, HDIM, INTERDIM, 4, partb, nullptr, nullptr);
  // out = sum(partials) + x1 + b2 + nb2   (f32)
  k_ffn2_reduce<<<ROWS * HDIM / 4 / 256, 256, 0, stream>>>(partb, x1b, b2, nb2, out);
}

// Round 15
// 142.749 us; speedup vs baseline: 1.1816x; 1.1816x over previous
//
#include <hip/hip_runtime.h>

typedef __bf16 bf16x8 __attribute__((ext_vector_type(8)));
typedef float f32x4 __attribute__((ext_vector_type(4)));
typedef unsigned short u16;
typedef unsigned long long u64;

#define HDIM 768
#define NHEADS 12
#define SEQ 1024
#define NBATCH 4
#define ROWS 4096      // B*T
#define QKV3 2304
#define INTERDIM 3072

__device__ __forceinline__ u16 f2bf(float f) {
  union { float f; unsigned int u; } v; v.f = f;
  unsigned int r = v.u + 0x7fffu + ((v.u >> 16) & 1u);
  return (u16)(r >> 16);
}

__device__ __forceinline__ float bf2f(u16 b) {
  union { unsigned int u; float f; } v; v.u = (unsigned int)b << 16;
  return v.f;
}

// async global->LDS, 16B per lane. LDS dest is wave-uniform base + lane*16.
__device__ __forceinline__ void gload16(const u16* g, u16* l) {
  __builtin_amdgcn_global_load_lds(
      (const __attribute__((address_space(1))) void*)g,
      (__attribute__((address_space(3))) void*)l, 16, 0, 0);
}

__device__ __forceinline__ unsigned ldsoff(const void* p) {
  return (unsigned)(unsigned long long)(const __attribute__((address_space(3))) char*)p;
}

// hardware transpose read: lane gets 4 bf16 at [a, a+32B, a+64B, a+96B]
__device__ __forceinline__ u64 tr8(unsigned a) {
  u64 r;
  asm volatile("ds_read_b64_tr_b16 %0, %1" : "=v"(r) : "v"(a));
  return r;
}

union B8 { u64 q[2]; bf16x8 v; };

// ---------------- fused pre-pass: x->bf16 + 4 weight transposes ----------------
__global__ __launch_bounds__(256) void k_prep(
    const float* __restrict__ x, u16* __restrict__ xb,
    const float* __restrict__ wqkv, u16* __restrict__ wqkvT,
    const float* __restrict__ wo, u16* __restrict__ woT,
    const float* __restrict__ w1, u16* __restrict__ w1T,
    const float* __restrict__ w2, u16* __restrict__ w2T) {
  __shared__ float tile[32][33];
  int bid = blockIdx.x, tid = threadIdx.x;
  if (bid < 3072) {
    int i = bid * 256 + tid;
    float4 f = reinterpret_cast<const float4*>(x)[i];
    ushort4 o;
    o.x = f2bf(f.x); o.y = f2bf(f.y); o.z = f2bf(f.z); o.w = f2bf(f.w);
    reinterpret_cast<ushort4*>(xb)[i] = o;
    return;
  }
  const float* in; u16* outp; int K, N, t;
  if (bid < 4800)      { in = wqkv; outp = wqkvT; K = 768;  N = 2304; t = bid - 3072; }
  else if (bid < 5376) { in = wo;   outp = woT;   K = 768;  N = 768;  t = bid - 4800; }
  else if (bid < 7680) { in = w1;   outp = w1T;   K = 768;  N = 3072; t = bid - 5376; }
  else                 { in = w2;   outp = w2T;   K = 3072; N = 768;  t = bid - 7680; }
  int ntx = N >> 5;
  int bx = t % ntx, by = t / ntx;
  int tx = tid & 31, ty = tid >> 5;
  int n0 = bx * 32, k0 = by * 32;
#pragma unroll
  for (int i = 0; i < 32; i += 8)
    tile[ty + i][tx] = in[(size_t)(k0 + ty + i) * N + n0 + tx];
  __syncthreads();
#pragma unroll
  for (int i = 0; i < 32; i += 8)
    outp[(size_t)(n0 + ty + i) * K + k0 + tx] = f2bf(tile[tx][ty + i]);
}

// ============ MFMA GEMM, BK=32, dbuf LDS, counted vmcnt (r12 config) ============
template<int BM, int BN, int MODE>
__global__ __launch_bounds__(256, 2) void k_gemm(
    const u16* __restrict__ A, const u16* __restrict__ Bt,
    int M, int N, int K, int ksplit,
    u16* __restrict__ obf,
    const float* __restrict__ e1, const float* __restrict__ e2) {
  constexpr int BK = 32;
  constexpr int WC = (BN == 128) ? 2 : 1;
  constexpr int WR = 4 / WC;
  constexpr int WM = BM / WR;
  constexpr int WN = BN / WC;
  constexpr int MFR = WM / 16;
  constexpr int NFR = WN / 16;
  constexpr int AISS = BM / 64;
  constexpr int BISS = BN / 64;
  constexpr int ISS = AISS + BISS;
  __shared__ u16 As[2][BM * BK];
  __shared__ u16 Bs[2][BN * BK];
  int tid = threadIdx.x, lane = tid & 63, wid = tid >> 6;
  int wr = wid / WC, wc = wid % WC;
  int fr = lane & 15, fg = lane >> 4, fk = fg * 8;

  int gx = gridDim.x;
  int nwg = gx * gridDim.y;
  int orig = blockIdx.y * gx + blockIdx.x;
  int swz = (orig & 7) * (nwg >> 3) + (orig >> 3);
  int bx = swz % gx, by = swz / gx;
  int m0 = by * BM, n0 = bx * BN;
  int Kc = K / ksplit, k0 = blockIdx.z * Kc;

  f32x4 acc[MFR][NFR] = {};

  int r = tid >> 2;
  int cswz = ((tid & 3) * 8) ^ (((r >> 1) & 3) << 3);
  const u16* Ag = A + (size_t)(m0 + r) * K + k0 + cswz;
  const u16* Bg = Bt + (size_t)(n0 + r) * K + k0 + cswz;

#define STAGE(t2) do {                                                   \
    int b_ = (t2) & 1; int kt_ = (t2) * BK;                              \
    _Pragma("unroll")                                                    \
    for (int i_ = 0; i_ < AISS; i_++)                                    \
      gload16(Ag + kt_ + (size_t)(i_ * 64) * K, &As[b_][i_ * 2048 + wid * 512]); \
    _Pragma("unroll")                                                    \
    for (int i_ = 0; i_ < BISS; i_++)                                    \
      gload16(Bg + kt_ + (size_t)(i_ * 64) * K, &Bs[b_][i_ * 2048 + wid * 512]); \
  } while (0)

  int ce = fk ^ (((fr >> 1) & 3) << 3);

  int nt = Kc / BK;
  STAGE(0);
  STAGE(1);

  for (int t = 0; t < nt; t++) {
    int cur = t & 1;
    if (t == nt - 1) {
      asm volatile("s_waitcnt vmcnt(0)\n\ts_barrier" ::: "memory");
    } else if constexpr (ISS == 6) {
      asm volatile("s_waitcnt vmcnt(6)\n\ts_barrier" ::: "memory");
    } else if constexpr (ISS == 4) {
      asm volatile("s_waitcnt vmcnt(4)\n\ts_barrier" ::: "memory");
    } else {
      asm volatile("s_waitcnt vmcnt(3)\n\ts_barrier" ::: "memory");
    }

    bf16x8 af[MFR], bv[NFR];
#pragma unroll
    for (int mi = 0; mi < MFR; mi++)
      af[mi] = *reinterpret_cast<const bf16x8*>(&As[cur][(wr * WM + mi * 16 + fr) * BK + ce]);
#pragma unroll
    for (int ni = 0; ni < NFR; ni++)
      bv[ni] = *reinterpret_cast<const bf16x8*>(&Bs[cur][(wc * WN + ni * 16 + fr) * BK + ce]);

    asm volatile("s_waitcnt lgkmcnt(0)\n\ts_barrier" ::: "memory");
    if (t + 2 < nt) STAGE(t + 2);

    __builtin_amdgcn_s_setprio(1);
#pragma unroll
    for (int mi = 0; mi < MFR; mi++)
#pragma unroll
      for (int ni = 0; ni < NFR; ni++)
        acc[mi][ni] = __builtin_amdgcn_mfma_f32_16x16x32_bf16(af[mi], bv[ni], acc[mi][ni], 0, 0, 0);
    __builtin_amdgcn_s_setprio(0);
  }
#undef STAGE

  u16* outp = (MODE == 3) ? obf + (size_t)blockIdx.z * ((size_t)M * N) : obf;
#pragma unroll
  for (int mi = 0; mi < MFR; mi++) {
#pragma unroll
    for (int ni = 0; ni < NFR; ni++) {
#pragma unroll
      for (int i = 0; i < 4; i++) {
        int row = m0 + wr * WM + mi * 16 + fg * 4 + i;
        int col = n0 + wc * WN + ni * 16 + fr;
        float v = acc[mi][ni][i];
        size_t idx = (size_t)row * N + col;
        if constexpr (MODE == 0) {
          outp[idx] = f2bf(v);
        } else if constexpr (MODE == 1) {
          outp[idx] = f2bf(e1[idx] + 0.2f * v + e2[col]);
        } else if constexpr (MODE == 2) {
          float t = v + e1[col];
          outp[idx] = f2bf(t > 0.f ? t : 0.f);
        } else {
          outp[idx] = f2bf(v);
        }
      }
    }
  }
}

// ---------------- ffn2 split-K reduce + residual + biases (bf16 inputs) ----------------
__global__ void k_ffn2_reduce(const u16* __restrict__ p, const u16* __restrict__ x1b,
                              const float* __restrict__ b2, const float* __restrict__ nb2,
                              float* __restrict__ out) {
  int i = blockIdx.x * 256 + threadIdx.x;
  int col4 = (i * 4) % HDIM;
  ushort4 xv = reinterpret_cast<const ushort4*>(x1b)[i];
  float4 bb = *reinterpret_cast<const float4*>(b2 + col4);
  float4 nn = *reinterpret_cast<const float4*>(nb2 + col4);
  float4 s;
  s.x = bf2f(xv.x) + bb.x + nn.x;
  s.y = bf2f(xv.y) + bb.y + nn.y;
  s.z = bf2f(xv.z) + bb.z + nn.z;
  s.w = bf2f(xv.w) + bb.w + nn.w;
#pragma unroll
  for (int z = 0; z < 4; z++) {
    ushort4 pv = reinterpret_cast<const ushort4*>(p + (size_t)z * ROWS * HDIM)[i];
    s.x += bf2f(pv.x); s.y += bf2f(pv.y); s.z += bf2f(pv.z); s.w += bf2f(pv.w);
  }
  reinterpret_cast<float4*>(out)[i] = s;
}

// ---------------- fused 2quad attention (8 waves, 128 q-rows/block) ----------------
// r12 structure + bank-rotation fix (r14 post-mortem):
//   V sub-block base: blk*128B + (blk&3)*32B  -> V writes conflict-free
//   P sub-block base: blk*128B + (blk&3)*8B   -> P writes conflict-free
// Rotations are uniform within each 16-lane tr8 group (V-rot depends on df,
// P-rot on fg-derived block), so tr8 semantics unchanged.
__global__ __launch_bounds__(512) void k_attn(
    const u16* __restrict__ qkv, const float* __restrict__ mask,
    const float* __restrict__ tau, u16* __restrict__ outp) {
  __shared__ u16 Ks[64 * 72];
  __shared__ u16 Vs[64 * 64 + 64];   // +64 elems: rotation overhang
  __shared__ u16 Ps[8][1040];        // +16 elems: rotation overhang
  int tid = threadIdx.x, lane = tid & 63, w = tid >> 6;
  int bid = blockIdx.x;
  int bh = bid % 48, t0i = bid / 48;
  int h = bh >> 2, b = bh & 3;
  int fr = lane & 15, fg = lane >> 4, fk = fg * 8;
  int rb = b * SEQ;
  float rs = 1.0f / (8.0f * tau[h]);
  float rs2 = rs * rs;

  int t0 = t0i * 128 + w * 16;
  const u16* qrow = qkv + (size_t)(rb + t0 + fr) * QKV3 + h * 64;
  bf16x8 aq0 = *reinterpret_cast<const bf16x8*>(qrow + fk);
  bf16x8 aq1 = *reinterpret_cast<const bf16x8*>(qrow + 32 + fk);

  f32x4 acco[4] = {};
  f32x4 accd = {};

  int sr = tid >> 3, c = tid & 7;
  const u16* kg = qkv + (size_t)(rb + sr) * QKV3 + HDIM + h * 64 + c * 8;
  const u16* vg = kg + HDIM;
  u16* kw = &Ks[sr * 72 + c * 8];
  // V: block = (sr>>2)*4 + dj, dj = c>>1; elem = blk*64 + (blk&3)*16 + (sr&3)*16 + (c&1)*8
  int vblkW = (sr >> 2) * 4 + (c >> 1);
  u16* vw = &Vs[vblkW * 64 + (vblkW & 3) * 16 + (sr & 3) * 16 + (c & 1) * 8];
  unsigned psb = ldsoff(&Ps[w][0]);
  unsigned vsb = ldsoff(Vs);

  __bf16 onev = (__bf16)1.0f;
  bf16x8 ones = {onev, onev, onev, onev, onev, onev, onev, onev};

  int4 kreg = *reinterpret_cast<const int4*>(kg);
  int4 vreg = *reinterpret_cast<const int4*>(vg);

  for (int st = 0; st < SEQ; st += 64) {
    __syncthreads();
    *reinterpret_cast<int4*>(kw) = kreg;
    *reinterpret_cast<int4*>(vw) = vreg;
    __syncthreads();
    if (st + 64 < SEQ) {
      kreg = *reinterpret_cast<const int4*>(kg + (size_t)(st + 64) * QKV3);
      vreg = *reinterpret_cast<const int4*>(vg + (size_t)(st + 64) * QKV3);
    }

#pragma unroll
    for (int sf = 0; sf < 4; sf++) {
      bf16x8 bk0 = *reinterpret_cast<const bf16x8*>(&Ks[(sf * 16 + fr) * 72 + fk]);
      bf16x8 bk1 = *reinterpret_cast<const bf16x8*>(&Ks[(sf * 16 + fr) * 72 + 32 + fk]);
      f32x4 s = {};
      s = __builtin_amdgcn_mfma_f32_16x16x32_bf16(aq0, bk0, s, 0, 0, 0);
      s = __builtin_amdgcn_mfma_f32_16x16x32_bf16(aq1, bk1, s, 0, 0, 0);
      float rm = rs2 * mask[b * SEQ + st + sf * 16 + fr];
      u64 pw = 0;
#pragma unroll
      for (int i = 0; i < 4; i++) {
        float wv = s[i] * s[i] * rm;
        pw |= (u64)f2bf(wv) << (16 * i);
      }
      // P: block = sf*4 + (fr>>2); elem = blk*64 + (blk&3)*4 + (fr&3)*16 + fg*4
      int pblk = sf * 4 + (fr >> 2);
      *reinterpret_cast<u64*>(&Ps[w][pblk * 64 + (pblk & 3) * 4 + (fr & 3) * 16 + fg * 4]) = pw;
    }
    asm volatile("s_waitcnt lgkmcnt(0)" ::: "memory");
    __builtin_amdgcn_sched_barrier(0);

    int rb0 = fg * 2, rb1 = fg * 2 + 1, rb2 = 8 + fg * 2, rb3 = 9 + fg * 2;
    u64 pa0 = tr8(psb + rb0 * 128 + (rb0 & 3) * 8 + fr * 2);
    u64 pa1 = tr8(psb + rb1 * 128 + (rb1 & 3) * 8 + fr * 2);
    u64 pa2 = tr8(psb + rb2 * 128 + (rb2 & 3) * 8 + fr * 2);
    u64 pa3 = tr8(psb + rb3 * 128 + (rb3 & 3) * 8 + fr * 2);
    u64 vb[4][4];
#pragma unroll
    for (int df = 0; df < 4; df++) {
#pragma unroll
      for (int j = 0; j < 4; j++) {
        int sg = (j >> 1) * 8 + fg * 2 + (j & 1);
        int vblk = sg * 4 + df;
        vb[df][j] = tr8(vsb + vblk * 128 + (vblk & 3) * 32 + fr * 2);
      }
    }
    asm volatile("s_waitcnt lgkmcnt(0)" ::: "memory");
    __builtin_amdgcn_sched_barrier(0);

    B8 ap0, ap1;
    ap0.q[0] = pa0; ap0.q[1] = pa1;
    ap1.q[0] = pa2; ap1.q[1] = pa3;
#pragma unroll
    for (int df = 0; df < 4; df++) {
      B8 b0, b1;
      b0.q[0] = vb[df][0]; b0.q[1] = vb[df][1];
      b1.q[0] = vb[df][2]; b1.q[1] = vb[df][3];
      acco[df] = __builtin_amdgcn_mfma_f32_16x16x32_bf16(ap0.v, b0.v, acco[df], 0, 0, 0);
      acco[df] = __builtin_amdgcn_mfma_f32_16x16x32_bf16(ap1.v, b1.v, acco[df], 0, 0, 0);
    }
    accd = __builtin_amdgcn_mfma_f32_16x16x32_bf16(ap0.v, ones, accd, 0, 0, 0);
    accd = __builtin_amdgcn_mfma_f32_16x16x32_bf16(ap1.v, ones, accd, 0, 0, 0);
  }

#pragma unroll
  for (int df = 0; df < 4; df++)
#pragma unroll
    for (int i = 0; i < 4; i++) {
      int t = t0 + fg * 4 + i;
      int col = h * 64 + df * 16 + fr;
      float o = acco[df][i] / (accd[i] + 1e-6f);
      outp[(size_t)(rb + t) * HDIM + col] = f2bf(o);
    }
}

extern "C" void kernel_launch(void* const* d_in, const int* in_sizes, int n_in,
                              void* d_out, int out_size, void* d_ws, size_t ws_size,
                              hipStream_t stream) {
  const float* x     = (const float*)d_in[0];
  const float* mask  = (const float*)d_in[1];
  const float* w_qkv = (const float*)d_in[2];
  const float* w_o   = (const float*)d_in[3];
  const float* tau   = (const float*)d_in[4];
  const float* w1    = (const float*)d_in[5];
  const float* b1    = (const float*)d_in[6];
  const float* w2    = (const float*)d_in[7];
  const float* b2    = (const float*)d_in[8];
  const float* nb1   = (const float*)d_in[9];
  const float* nb2   = (const float*)d_in[10];
  float* out = (float*)d_out;
  (void)ws_size; (void)in_sizes; (void)n_in; (void)out_size;

  char* base = (char*)d_ws;
  u16* partb = (u16*)base;                    // [4][ROWS][HDIM] bf16, live only in ffn2
  u16* xb    = (u16*)(base);
  u16* wqkvT = (u16*)(base + 6291456);
  u16* woT   = (u16*)(base + 9830400);
  u16* w1T   = (u16*)(base + 11010048);
  u16* qkvb  = (u16*)(base + 15728640);       // dead after attn
  u16* attnb = (u16*)(base + 34603008);
  u16* x1b   = (u16*)(base + 40894464);       // live through reduce
  u16* w2T   = (u16*)(base + 50331648);
  u16* hb    = (u16*)(base + 67633152);

  k_prep<<<9984, 256, 0, stream>>>(x, xb, w_qkv, wqkvT, w_o, woT, w1, w1T, w2, w2T);

  // qkv = x @ w_qkv -> bf16   (grid 18x16 = 288, 256-tile)
  k_gemm<256, 128, 0><<<dim3(QKV3 / 128, ROWS / 256), 256, 0, stream>>>(
      xb, wqkvT, ROWS, QKV3, HDIM, 1, qkvb, nullptr, nullptr);
  // attention (1D bh-chunked grid: 8 * 48 = 384, 512 threads)
  k_attn<<<384, 512, 0, stream>>>(qkvb, mask, tau, attnb);
  // x1 = bf16(x + 0.2*(attn @ w_o) + nb1)   (grid 12x32 = 384)
  k_gemm<128, 64, 1><<<dim3(HDIM / 64, ROWS / 128), 256, 0, stream>>>(
      attnb, woT, ROWS, HDIM, HDIM, 1, x1b, x, nb1);
  // h = relu(x1 @ w1 + b1)   (grid 24x16 = 384, 256-tile)
  k_gemm<256, 128, 2><<<dim3(INTERDIM / 128, ROWS / 256), 256, 0, stream>>>(
      x1b, w1T, ROWS, INTERDIM, HDIM, 1, hb, b1, nullptr);
  // ffn2 split-K=4 bf16 partials   (grid 6x16x4 = 384, 256-tile)
  k_gemm<256, 128, 3><<<dim3(HDIM / 128, ROWS / 256, 4), 256, 0, stream>>>(
      hb, w2T, ROWS, HDIM, INTERDIM, 4, partb, nullptr, nullptr);
  // out = sum(partials) + x1 + b2 + nb2   (f32)
  k_ffn2_reduce<<<ROWS * HDIM / 4 / 256, 256, 0, stream>>>(partb, x1b, b2, nb2, out);
}